// Round 7
// baseline (1219.482 us; speedup 1.0000x reference)
//
#include <hip/hip_runtime.h>
#include <hip/hip_bf16.h>
#include <stdint.h>

#define NT   8192
#define DIN  2048
#define DOUT 2048
#define NSP  8
#define BK   32

// Guide §3 (HW-verified on gfx950/ROCm7): bf16 MFMA fragments are short8.
typedef short  s16x8 __attribute__((ext_vector_type(8)));
typedef float  f32x4 __attribute__((ext_vector_type(4)));

static_assert(sizeof(s16x8) == 16, "s16x8 must be 16B");

__device__ __forceinline__ f32x4 mfma_bf16(s16x8 a, s16x8 b, f32x4 c) {
  return __builtin_amdgcn_mfma_f32_16x16x32_bf16(a, b, c, 0, 0, 0);
}

// async global->LDS, 16B per lane. HW semantics (m104/m108): dest is
// wave-uniform base + lane*16 — our per-lane loff is exactly lane-linear.
__device__ __forceinline__ void async16(const void* g, void* l) {
  __builtin_amdgcn_global_load_lds(
      (const __attribute__((address_space(1))) uint32_t*)g,
      (__attribute__((address_space(3))) uint32_t*)l, 16, 0, 0);
}

// fp32 -> bf16 bits, round-to-nearest-even
__device__ __forceinline__ ushort f2bf_rne(float f) {
  uint32_t u = __float_as_uint(f);
  uint32_t r = (u + 0x7fffu + ((u >> 16) & 1u)) >> 16;
  return (ushort)r;
}
__device__ __forceinline__ float bf2f(ushort s) {
  return __uint_as_float(((uint32_t)s) << 16);
}

// ---------------- x split-convert: x (fp32 [T][D]) -> xhi, xlo (bf16 [T][D]) --
__global__ void k_convert_x(const float* __restrict__ x,
                            ushort* __restrict__ xhi, ushort* __restrict__ xlo) {
  int idx = blockIdx.x * blockDim.x + threadIdx.x;  // 8 elems / thread
  const float4* xv = (const float4*)x;
  float4 v0 = xv[2 * idx], v1 = xv[2 * idx + 1];
  float v[8] = {v0.x, v0.y, v0.z, v0.w, v1.x, v1.y, v1.z, v1.w};
  union { ushort u[8]; int4 q; } H, L;
#pragma unroll
  for (int i = 0; i < 8; i++) {
    ushort hb = f2bf_rne(v[i]);
    H.u[i] = hb;
    L.u[i] = f2bf_rne(v[i] - bf2f(hb));
  }
  ((int4*)xhi)[idx] = H.q;
  ((int4*)xlo)[idx] = L.q;
}

// -------- W split-convert + transpose: W [e][k][o] -> Wt[(eoff+e)][o][k] -----
__global__ void k_convert_w(const float* __restrict__ W,
                            ushort* __restrict__ wthi, ushort* __restrict__ wtlo,
                            int eoff) {
  __shared__ float tile[32][33];   // 33-stride: transpose read hits 32 banks
  const int e = blockIdx.z;
  const float* Wm = W + (size_t)e * DIN * DOUT;
  const int k0 = blockIdx.x * 32, o0 = blockIdx.y * 32;
  const int r = threadIdx.x >> 5, c = threadIdx.x & 31;
#pragma unroll
  for (int i = 0; i < 4; i++) {
    int rr = r + i * 8;
    tile[rr][c] = Wm[(size_t)(k0 + rr) * DOUT + o0 + c];
  }
  __syncthreads();
  const size_t obase = (size_t)(eoff + e) * DOUT;
#pragma unroll
  for (int i = 0; i < 4; i++) {
    int rr = r + i * 8;                      // row within o-tile
    float val = tile[c][rr];                 // = W[k0+c][o0+rr]
    size_t di = (obase + o0 + rr) * (size_t)DIN + (size_t)(k0 + c);
    ushort hb = f2bf_rne(val);
    wthi[di] = hb;
    wtlo[di] = f2bf_rne(val - bf2f(hb));
  }
}

// ---------------- router: gates + per-expert token lists ---------------------
__global__ void k_router(const float* __restrict__ x, const float* __restrict__ Wr,
                         const float* __restrict__ br,
                         int* __restrict__ counts, int* __restrict__ tok_list,
                         float* __restrict__ w_list) {
  const int wave = threadIdx.x >> 6, lane = threadIdx.x & 63;
  const int t = blockIdx.x * 4 + wave;
  const float* xrow = x + (size_t)t * DIN;
  float acc[NSP];
#pragma unroll
  for (int e = 0; e < NSP; e++) acc[e] = 0.f;
  for (int d = lane; d < DIN; d += 64) {
    float xv = xrow[d];
    const float* wr = Wr + d * NSP;
#pragma unroll
    for (int e = 0; e < NSP; e++) acc[e] += xv * wr[e];
  }
#pragma unroll
  for (int e = 0; e < NSP; e++) {
#pragma unroll
    for (int off = 32; off > 0; off >>= 1) acc[e] += __shfl_xor(acc[e], off, 64);
  }
  if (lane == 0) {
    float lg[NSP], mx = -1e30f;
#pragma unroll
    for (int e = 0; e < NSP; e++) { lg[e] = acc[e] + br[e]; mx = fmaxf(mx, lg[e]); }
    float p[NSP], s = 0.f;
#pragma unroll
    for (int e = 0; e < NSP; e++) { p[e] = expf(lg[e] - mx); s += p[e]; }
    int i0 = 0;
#pragma unroll
    for (int e = 1; e < NSP; e++) if (p[e] > p[i0]) i0 = e;   // strict >: first max
    int i1 = (i0 == 0) ? 1 : 0;                               // == lax.top_k ties
#pragma unroll
    for (int e = 0; e < NSP; e++) if (e != i0 && p[e] > p[i1]) i1 = e;
    float p0 = p[i0] / s, p1 = p[i1] / s;
    float denom = p0 + p1 + 1e-6f;
    float w0 = p0 / denom, w1 = p1 / denom;
    int s0 = atomicAdd(&counts[i0], 1);
    tok_list[i0 * NT + s0] = t; w_list[i0 * NT + s0] = w0;
    int s1 = atomicAdd(&counts[i1], 1);
    tok_list[i1 * NT + s1] = t; w_list[i1 * NT + s1] = w1;
  }
}

// ---------------- split-bf16 MFMA GEMM (128x128 tile, BK=32, 4 waves) --------
// A = x rows (gathered for sparse), B^T = Wt[wi] ([o][k], k contiguous).
// acc += Ah*Bh + Al*Bh + Ah*Bl  (fp32 MFMA accumulate; lo*lo dropped ~2^-18).
// LDS 33KB -> 3 blocks/CU with launch_bounds(256,3) [m132: 64KB LDS cost 40%].
template <bool SPARSE>
__global__ __launch_bounds__(256, 3) void k_moe_gemm(
    const ushort* __restrict__ xhi, const ushort* __restrict__ xlo,
    const ushort* __restrict__ wthi, const ushort* __restrict__ wtlo,
    const float* __restrict__ bias, const int* __restrict__ counts,
    const int* __restrict__ tok_list, const float* __restrict__ w_list,
    float* __restrict__ y) {
  const int e = SPARSE ? blockIdx.z : 0;
  const int wi = SPARSE ? (1 + e) : 0;
  int cnt = NT;
  if (SPARSE) {
    cnt = counts[e];
    if ((int)blockIdx.y * 128 >= cnt) return;
  }
  const int row0 = blockIdx.y * 128;
  const int col0 = blockIdx.x * 128;

  __shared__ __align__(16) ushort sAh[128 * BK];
  __shared__ __align__(16) ushort sAl[128 * BK];
  __shared__ __align__(16) ushort sBh[128 * BK];
  __shared__ __align__(16) ushort sBl[128 * BK];
  __shared__ int   s_tok[128];
  __shared__ float s_w[128];

  const int tid = threadIdx.x;
  const int wave = tid >> 6, lane = tid & 63;

  if (SPARSE) {
    if (tid < 128) {
      int slot = row0 + tid;
      int tk = 0; float w = 0.f;
      if (slot < cnt) { tk = tok_list[e * NT + slot]; w = w_list[e * NT + slot]; }
      s_tok[tid] = tk; s_w[tid] = w;
    }
    __syncthreads();
  }

  // Staging: wave owns rows [wave*32, wave*32+32), 2 issues x 16 rows / array.
  // Row = 64B = 4 chunks of 16B; physical slot p holds logical chunk p^(r&3).
  // Source pre-swizzled so LDS dest stays lane-linear (m173 / rule #21).
  const int lr = lane >> 2, pp = lane & 3;
  const ushort* gAh[2]; const ushort* gAl[2];
  const ushort* gBh[2]; const ushort* gBl[2];
  int loff[2];
#pragma unroll
  for (int j = 0; j < 2; j++) {
    int r = wave * 32 + j * 16 + lr;
    int xoff = ((pp ^ (r & 3)) << 3);  // element offset of swizzled 8-elem chunk
    int tk = SPARSE ? s_tok[r] : (row0 + r);
    gAh[j] = xhi + (size_t)tk * DIN + xoff;
    gAl[j] = xlo + (size_t)tk * DIN + xoff;
    size_t brow = ((size_t)wi * DOUT + (size_t)(col0 + r)) * DIN + xoff;
    gBh[j] = wthi + brow;
    gBl[j] = wtlo + brow;
    loff[j] = r * BK + pp * 8;  // ushort index; byte = r*64 + pp*16
  }

  f32x4 acc[4][4];
#pragma unroll
  for (int m = 0; m < 4; m++)
#pragma unroll
    for (int n = 0; n < 4; n++) acc[m][n] = (f32x4){0.f, 0.f, 0.f, 0.f};

  const int wm = (wave >> 1) * 64, wn = (wave & 1) * 64;
  const int fr = lane & 15, fg = lane >> 4;   // frag row / 8-elem k-group

  for (int kt = 0; kt < DIN / BK; kt++) {
    const int k0 = kt * BK;
#pragma unroll
    for (int j = 0; j < 2; j++) {
      async16(gAh[j] + k0, &sAh[loff[j]]);
      async16(gAl[j] + k0, &sAl[loff[j]]);
      async16(gBh[j] + k0, &sBh[loff[j]]);
      async16(gBl[j] + k0, &sBl[loff[j]]);
    }
    __syncthreads();  // compiler drains vmcnt before barrier

    s16x8 ah[4], al[4], bh[4], bl[4];
#pragma unroll
    for (int m = 0; m < 4; m++) {
      int r = wm + m * 16 + fr;
      int sl = ((fg ^ (r & 3)) << 3);
      ah[m] = *(const s16x8*)&sAh[r * BK + sl];
      al[m] = *(const s16x8*)&sAl[r * BK + sl];
    }
#pragma unroll
    for (int n = 0; n < 4; n++) {
      int c = wn + n * 16 + fr;
      int sl = ((fg ^ (c & 3)) << 3);
      bh[n] = *(const s16x8*)&sBh[c * BK + sl];
      bl[n] = *(const s16x8*)&sBl[c * BK + sl];
    }
#pragma unroll
    for (int m = 0; m < 4; m++)
#pragma unroll
      for (int n = 0; n < 4; n++) {
        acc[m][n] = mfma_bf16(ah[m], bh[n], acc[m][n]);
        acc[m][n] = mfma_bf16(al[m], bh[n], acc[m][n]);
        acc[m][n] = mfma_bf16(ah[m], bl[n], acc[m][n]);
      }
    __syncthreads();
  }

  // Epilogue. C/D layout: col = lane&15, row = (lane>>4)*4 + reg (m89-verified).
#pragma unroll
  for (int n = 0; n < 4; n++) {
    int col = col0 + wn + n * 16 + fr;
    float bc = SPARSE ? bias[e * DOUT + col] : bias[col];
#pragma unroll
    for (int m = 0; m < 4; m++) {
#pragma unroll
      for (int q = 0; q < 4; q++) {
        int lrow = wm + m * 16 + fg * 4 + q;
        float v = acc[m][n][q];
        if (SPARSE) {
          if (row0 + lrow < cnt) {
            float g = s_w[lrow];
            atomicAdd(&y[(size_t)s_tok[lrow] * DOUT + col], g * (v + bc));
          }
        } else {
          y[(size_t)(row0 + lrow) * DOUT + col] = v + bc;  // N_SHARED==1
        }
      }
    }
  }
}

// ============ Tier-B fallback: fp32 vector GEMM, tiny workspace ==============
// Only used if ws_size can't hold the split/transpose buffers. 64x64 tile,
// 256 threads, 4x4 outputs/thread, fp32 FMA. W read as stored [k][o].
template <bool SPARSE>
__global__ void k_fb_gemm(const float* __restrict__ x, const float* __restrict__ W,
                          const float* __restrict__ bias,
                          const int* __restrict__ counts,
                          const int* __restrict__ tok_list,
                          const float* __restrict__ w_list,
                          float* __restrict__ y) {
  const int e = SPARSE ? blockIdx.z : 0;
  int cnt = NT;
  if (SPARSE) {
    cnt = counts[e];
    if ((int)blockIdx.y * 64 >= cnt) return;
  }
  const int row0 = blockIdx.y * 64, col0 = blockIdx.x * 64;
  const float* Wm = W + (SPARSE ? (size_t)e * DIN * DOUT : 0);

  __shared__ float sA[64][17];
  __shared__ float sB[16][65];
  __shared__ int   s_tok[64];
  __shared__ float s_w[64];

  const int tid = threadIdx.x;
  if (SPARSE) {
    if (tid < 64) {
      int slot = row0 + tid;
      int tk = 0; float w = 0.f;
      if (slot < cnt) { tk = tok_list[e * NT + slot]; w = w_list[e * NT + slot]; }
      s_tok[tid] = tk; s_w[tid] = w;
    }
    __syncthreads();
  }

  const int ar = tid >> 2, ak = (tid & 3) * 4;     // A: row, 4-k chunk
  const int bk = tid >> 4, bc4 = (tid & 15) * 4;   // B: k-row, 4-col chunk
  const int tm = tid >> 4, tn = tid & 15;          // compute: 4x4 at (tm*4, tn*4)

  float acc[4][4];
#pragma unroll
  for (int m = 0; m < 4; m++)
#pragma unroll
    for (int n = 0; n < 4; n++) acc[m][n] = 0.f;

  const int tkA = SPARSE ? s_tok[ar] : (row0 + ar);

  for (int k0 = 0; k0 < DIN; k0 += 16) {
    float4 va = *(const float4*)&x[(size_t)tkA * DIN + k0 + ak];
    float4 vb = *(const float4*)&Wm[(size_t)(k0 + bk) * DOUT + col0 + bc4];
    sA[ar][ak]     = va.x; sA[ar][ak + 1] = va.y;
    sA[ar][ak + 2] = va.z; sA[ar][ak + 3] = va.w;
    sB[bk][bc4]     = vb.x; sB[bk][bc4 + 1] = vb.y;
    sB[bk][bc4 + 2] = vb.z; sB[bk][bc4 + 3] = vb.w;
    __syncthreads();
#pragma unroll
    for (int kk = 0; kk < 16; kk++) {
      float a0 = sA[tm * 4 + 0][kk], a1 = sA[tm * 4 + 1][kk];
      float a2 = sA[tm * 4 + 2][kk], a3 = sA[tm * 4 + 3][kk];
#pragma unroll
      for (int n = 0; n < 4; n++) {
        float b = sB[kk][tn * 4 + n];
        acc[0][n] += a0 * b; acc[1][n] += a1 * b;
        acc[2][n] += a2 * b; acc[3][n] += a3 * b;
      }
    }
    __syncthreads();
  }

#pragma unroll
  for (int m = 0; m < 4; m++) {
    int lrow = tm * 4 + m;
#pragma unroll
    for (int n = 0; n < 4; n++) {
      int col = col0 + tn * 4 + n;
      float bcv = SPARSE ? bias[e * DOUT + col] : bias[col];
      if (SPARSE) {
        if (row0 + lrow < cnt) {
          atomicAdd(&y[(size_t)s_tok[lrow] * DOUT + col],
                    s_w[lrow] * (acc[m][n] + bcv));
        }
      } else {
        y[(size_t)(row0 + lrow) * DOUT + col] = acc[m][n] + bcv;
      }
    }
  }
}

// Tier-C: zero d_out (safe, loud validation failure — never faults).
__global__ void k_zero(float* __restrict__ y, int n) {
  for (int i = blockIdx.x * blockDim.x + threadIdx.x; i < n;
       i += gridDim.x * blockDim.x)
    y[i] = 0.f;
}

extern "C" void kernel_launch(void* const* d_in, const int* in_sizes, int n_in,
                              void* d_out, int out_size, void* d_ws, size_t ws_size,
                              hipStream_t stream) {
  (void)in_sizes; (void)n_in;
  const float* x   = (const float*)d_in[0];
  const float* Wsh = (const float*)d_in[1];
  const float* bsh = (const float*)d_in[2];
  const float* Wr  = (const float*)d_in[3];
  const float* br  = (const float*)d_in[4];
  const float* Wsp = (const float*)d_in[5];
  const float* bsp = (const float*)d_in[6];
  float* y = (float*)d_out;

  char* ws = (char*)d_ws;
  size_t off = 0;
  auto alloc = [&](size_t bytes) {
    off = (off + 255) & ~(size_t)255;
    void* p = ws + off;
    off += bytes;
    return p;
  };
  int*    counts   = (int*)alloc(NSP * sizeof(int));
  int*    tok_list = (int*)alloc((size_t)NSP * NT * sizeof(int));
  float*  w_list   = (float*)alloc((size_t)NSP * NT * sizeof(float));
  const size_t NEED_FB = off;                     // ~0.53 MB
  ushort* xhi      = (ushort*)alloc((size_t)NT * DIN * 2);
  ushort* xlo      = (ushort*)alloc((size_t)NT * DIN * 2);
  ushort* wthi     = (ushort*)alloc((size_t)9 * DOUT * DIN * 2);
  ushort* wtlo     = (ushort*)alloc((size_t)9 * DOUT * DIN * 2);
  const size_t NEED_FAST = off;                   // ~218.6 MB

  if (ws_size < NEED_FB) {                        // Tier C: no usable scratch
    k_zero<<<2048, 256, 0, stream>>>(y, out_size);
    return;
  }

  hipMemsetAsync(counts, 0, NSP * sizeof(int), stream);
  k_router<<<NT / 4, 256, 0, stream>>>(x, Wr, br, counts, tok_list, w_list);

  if (ws_size >= NEED_FAST) {                     // Tier A: fast split-bf16 MFMA
    k_convert_x<<<(NT * DIN / 8) / 256, 256, 0, stream>>>(x, xhi, xlo);
    k_convert_w<<<dim3(DIN / 32, DOUT / 32, 1), 256, 0, stream>>>(Wsh, wthi, wtlo, 0);
    k_convert_w<<<dim3(DIN / 32, DOUT / 32, NSP), 256, 0, stream>>>(Wsp, wthi, wtlo, 1);
    // shared expert: plain store (initializes all of y)
    k_moe_gemm<false><<<dim3(DOUT / 128, NT / 128, 1), 256, 0, stream>>>(
        xhi, xlo, wthi, wtlo, bsh, counts, tok_list, w_list, y);
    // sparse experts: gathered rows, atomicAdd epilogue (ordered after shared)
    k_moe_gemm<true><<<dim3(DOUT / 128, NT / 128, NSP), 256, 0, stream>>>(
        xhi, xlo, wthi, wtlo, bsp, counts, tok_list, w_list, y);
  } else {                                        // Tier B: fp32 fallback GEMM
    k_fb_gemm<false><<<dim3(DOUT / 64, NT / 64, 1), 256, 0, stream>>>(
        x, Wsh, bsh, counts, tok_list, w_list, y);
    k_fb_gemm<true><<<dim3(DOUT / 64, NT / 64, NSP), 256, 0, stream>>>(
        x, Wsp, bsp, counts, tok_list, w_list, y);
  }
}

// Round 8
// 790.716 us; speedup vs baseline: 1.5423x; 1.5423x over previous
//
#include <hip/hip_runtime.h>
#include <hip/hip_bf16.h>
#include <stdint.h>

#define NT   8192
#define DIN  2048
#define DOUT 2048
#define NSP  8
#define BK   64

// fp16 MFMA fragments: 8 halves = 4 VGPRs (guide §3, same mapping as bf16).
typedef _Float16 f16x8 __attribute__((ext_vector_type(8)));
typedef float    f32x4 __attribute__((ext_vector_type(4)));

static_assert(sizeof(f16x8) == 16, "f16x8 must be 16B");

__device__ __forceinline__ f32x4 mfma_f16(f16x8 a, f16x8 b, f32x4 c) {
  return __builtin_amdgcn_mfma_f32_16x16x32_f16(a, b, c, 0, 0, 0);
}

// async global->LDS, 16B per lane. HW semantics (m104/m108): dest is
// wave-uniform base + lane*16 — our per-lane loff is exactly lane-linear.
__device__ __forceinline__ void async16(const void* g, void* l) {
  __builtin_amdgcn_global_load_lds(
      (const __attribute__((address_space(1))) uint32_t*)g,
      (__attribute__((address_space(3))) uint32_t*)l, 16, 0, 0);
}

// ---------------- x convert: fp32 [T][D] -> fp16 [T][D] ----------------------
__global__ void k_convert_x(const float* __restrict__ x,
                            _Float16* __restrict__ xh) {
  int idx = blockIdx.x * blockDim.x + threadIdx.x;  // 8 elems / thread
  const float4* xv = (const float4*)x;
  float4 v0 = xv[2 * idx], v1 = xv[2 * idx + 1];
  union { _Float16 h[8]; int4 q; } H;
  H.h[0] = (_Float16)v0.x; H.h[1] = (_Float16)v0.y;
  H.h[2] = (_Float16)v0.z; H.h[3] = (_Float16)v0.w;
  H.h[4] = (_Float16)v1.x; H.h[5] = (_Float16)v1.y;
  H.h[6] = (_Float16)v1.z; H.h[7] = (_Float16)v1.w;
  ((int4*)xh)[idx] = H.q;
}

// -------- W convert + transpose: W [e][k][o] fp32 -> Wt[(eoff+e)][o][k] fp16 -
__global__ void k_convert_w(const float* __restrict__ W,
                            _Float16* __restrict__ wth, int eoff) {
  __shared__ float tile[32][33];   // 33-stride: transpose read hits 32 banks
  const int e = blockIdx.z;
  const float* Wm = W + (size_t)e * DIN * DOUT;
  const int k0 = blockIdx.x * 32, o0 = blockIdx.y * 32;
  const int r = threadIdx.x >> 5, c = threadIdx.x & 31;
#pragma unroll
  for (int i = 0; i < 4; i++) {
    int rr = r + i * 8;
    tile[rr][c] = Wm[(size_t)(k0 + rr) * DOUT + o0 + c];
  }
  __syncthreads();
  const size_t obase = (size_t)(eoff + e) * DOUT;
#pragma unroll
  for (int i = 0; i < 4; i++) {
    int rr = r + i * 8;                      // row within o-tile
    float val = tile[c][rr];                 // = W[k0+c][o0+rr]
    wth[(obase + o0 + rr) * (size_t)DIN + (size_t)(k0 + c)] = (_Float16)val;
  }
}

// ---------------- router: gates + per-expert token lists ---------------------
__global__ void k_router(const float* __restrict__ x, const float* __restrict__ Wr,
                         const float* __restrict__ br,
                         int* __restrict__ counts, int* __restrict__ tok_list,
                         float* __restrict__ w_list) {
  const int wave = threadIdx.x >> 6, lane = threadIdx.x & 63;
  const int t = blockIdx.x * 4 + wave;
  const float* xrow = x + (size_t)t * DIN;
  float acc[NSP];
#pragma unroll
  for (int e = 0; e < NSP; e++) acc[e] = 0.f;
  for (int d = lane; d < DIN; d += 64) {
    float xv = xrow[d];
    const float* wr = Wr + d * NSP;
#pragma unroll
    for (int e = 0; e < NSP; e++) acc[e] += xv * wr[e];
  }
#pragma unroll
  for (int e = 0; e < NSP; e++) {
#pragma unroll
    for (int off = 32; off > 0; off >>= 1) acc[e] += __shfl_xor(acc[e], off, 64);
  }
  if (lane == 0) {
    float lg[NSP], mx = -1e30f;
#pragma unroll
    for (int e = 0; e < NSP; e++) { lg[e] = acc[e] + br[e]; mx = fmaxf(mx, lg[e]); }
    float p[NSP], s = 0.f;
#pragma unroll
    for (int e = 0; e < NSP; e++) { p[e] = expf(lg[e] - mx); s += p[e]; }
    int i0 = 0;
#pragma unroll
    for (int e = 1; e < NSP; e++) if (p[e] > p[i0]) i0 = e;   // strict >: first max
    int i1 = (i0 == 0) ? 1 : 0;                               // == lax.top_k ties
#pragma unroll
    for (int e = 0; e < NSP; e++) if (e != i0 && p[e] > p[i1]) i1 = e;
    float p0 = p[i0] / s, p1 = p[i1] / s;
    float denom = p0 + p1 + 1e-6f;
    float w0 = p0 / denom, w1 = p1 / denom;
    int s0 = atomicAdd(&counts[i0], 1);
    tok_list[i0 * NT + s0] = t; w_list[i0 * NT + s0] = w0;
    int s1 = atomicAdd(&counts[i1], 1);
    tok_list[i1 * NT + s1] = t; w_list[i1 * NT + s1] = w1;
  }
}

// ------------- fp16 MFMA GEMM (m97 shape: 128x128 tile, BK=64, 4 waves) ------
// A = x rows (gathered for sparse), B^T = Wt[wi] ([o][k], k contiguous).
// Single fp16 term: per-output err std ~2e-4 (vs observed absmax 0.0156,
// which is routing-tie structural, not GEMM precision). 32KB LDS, 3 blk/CU.
template <bool SPARSE>
__global__ __launch_bounds__(256, 3) void k_moe_gemm(
    const _Float16* __restrict__ xh, const _Float16* __restrict__ wth,
    const float* __restrict__ bias, const int* __restrict__ counts,
    const int* __restrict__ tok_list, const float* __restrict__ w_list,
    float* __restrict__ y) {
  const int e = SPARSE ? blockIdx.z : 0;
  const int wi = SPARSE ? (1 + e) : 0;
  int cnt = NT;
  if (SPARSE) {
    cnt = counts[e];
    if ((int)blockIdx.y * 128 >= cnt) return;
  }
  const int row0 = blockIdx.y * 128;
  const int col0 = blockIdx.x * 128;

  __shared__ __align__(16) _Float16 sA[128 * BK];
  __shared__ __align__(16) _Float16 sB[128 * BK];
  __shared__ int   s_tok[128];
  __shared__ float s_w[128];

  const int tid = threadIdx.x;
  const int wave = tid >> 6, lane = tid & 63;

  if (SPARSE) {
    if (tid < 128) {
      int slot = row0 + tid;
      int tk = 0; float w = 0.f;
      if (slot < cnt) { tk = tok_list[e * NT + slot]; w = w_list[e * NT + slot]; }
      s_tok[tid] = tk; s_w[tid] = w;
    }
    __syncthreads();
  }

  // Staging: wave owns rows [wave*32,+32), 4 issues x 8 rows per array.
  // Row = 128B = 8 chunks of 16B; physical slot p holds logical chunk p^(r&7).
  // Source pre-swizzled so LDS dest stays lane-linear (m173 / rule #21):
  // dest byte = base_j + lane*16 exactly (row stride 128B = 8 lanes x 16B).
  const int lr = lane >> 3, pp = lane & 7;
  const _Float16* gA[4]; const _Float16* gB[4];
  int loff[4];
#pragma unroll
  for (int j = 0; j < 4; j++) {
    int r = wave * 32 + j * 8 + lr;
    int xoff = ((pp ^ (r & 7)) << 3);  // element offset of swizzled 8-elem chunk
    int tk = SPARSE ? s_tok[r] : (row0 + r);
    gA[j] = xh + (size_t)tk * DIN + xoff;
    gB[j] = wth + ((size_t)wi * DOUT + (size_t)(col0 + r)) * DIN + xoff;
    loff[j] = r * BK + pp * 8;  // fp16 index; byte = r*128 + pp*16
  }

  f32x4 acc[4][4];
#pragma unroll
  for (int m = 0; m < 4; m++)
#pragma unroll
    for (int n = 0; n < 4; n++) acc[m][n] = (f32x4){0.f, 0.f, 0.f, 0.f};

  const int wm = (wave >> 1) * 64, wn = (wave & 1) * 64;
  const int fr = lane & 15, fg = lane >> 4;   // frag row / 8-elem k-group

  for (int kt = 0; kt < DIN / BK; kt++) {
    const int k0 = kt * BK;
#pragma unroll
    for (int j = 0; j < 4; j++) {
      async16(gA[j] + k0, &sA[loff[j]]);
      async16(gB[j] + k0, &sB[loff[j]]);
    }
    __syncthreads();  // compiler drains vmcnt before barrier

#pragma unroll
    for (int ks = 0; ks < 2; ks++) {
      f16x8 ah[4], bh[4];
#pragma unroll
      for (int m = 0; m < 4; m++) {
        int r = wm + m * 16 + fr;
        int sl = (((ks * 4 + fg) ^ (r & 7)) << 3);
        ah[m] = *(const f16x8*)&sA[r * BK + sl];
      }
#pragma unroll
      for (int n = 0; n < 4; n++) {
        int c = wn + n * 16 + fr;
        int sl = (((ks * 4 + fg) ^ (c & 7)) << 3);
        bh[n] = *(const f16x8*)&sB[c * BK + sl];
      }
#pragma unroll
      for (int m = 0; m < 4; m++)
#pragma unroll
        for (int n = 0; n < 4; n++)
          acc[m][n] = mfma_f16(ah[m], bh[n], acc[m][n]);
    }
    __syncthreads();
  }

  // Epilogue. C/D layout: col = lane&15, row = (lane>>4)*4 + reg (m89-verified).
#pragma unroll
  for (int n = 0; n < 4; n++) {
    int col = col0 + wn + n * 16 + fr;
    float bc = SPARSE ? bias[e * DOUT + col] : bias[col];
#pragma unroll
    for (int m = 0; m < 4; m++) {
#pragma unroll
      for (int q = 0; q < 4; q++) {
        int lrow = wm + m * 16 + fg * 4 + q;
        float v = acc[m][n][q];
        if (SPARSE) {
          if (row0 + lrow < cnt) {
            float g = s_w[lrow];
            atomicAdd(&y[(size_t)s_tok[lrow] * DOUT + col], g * (v + bc));
          }
        } else {
          y[(size_t)(row0 + lrow) * DOUT + col] = v + bc;  // N_SHARED==1
        }
      }
    }
  }
}

// ============ Tier-B fallback: fp32 vector GEMM, tiny workspace ==============
template <bool SPARSE>
__global__ void k_fb_gemm(const float* __restrict__ x, const float* __restrict__ W,
                          const float* __restrict__ bias,
                          const int* __restrict__ counts,
                          const int* __restrict__ tok_list,
                          const float* __restrict__ w_list,
                          float* __restrict__ y) {
  const int e = SPARSE ? blockIdx.z : 0;
  int cnt = NT;
  if (SPARSE) {
    cnt = counts[e];
    if ((int)blockIdx.y * 64 >= cnt) return;
  }
  const int row0 = blockIdx.y * 64, col0 = blockIdx.x * 64;
  const float* Wm = W + (SPARSE ? (size_t)e * DIN * DOUT : 0);

  __shared__ float sA[64][17];
  __shared__ float sB[16][65];
  __shared__ int   s_tok[64];
  __shared__ float s_w[64];

  const int tid = threadIdx.x;
  if (SPARSE) {
    if (tid < 64) {
      int slot = row0 + tid;
      int tk = 0; float w = 0.f;
      if (slot < cnt) { tk = tok_list[e * NT + slot]; w = w_list[e * NT + slot]; }
      s_tok[tid] = tk; s_w[tid] = w;
    }
    __syncthreads();
  }

  const int ar = tid >> 2, ak = (tid & 3) * 4;
  const int bk = tid >> 4, bc4 = (tid & 15) * 4;
  const int tm = tid >> 4, tn = tid & 15;

  float acc[4][4];
#pragma unroll
  for (int m = 0; m < 4; m++)
#pragma unroll
    for (int n = 0; n < 4; n++) acc[m][n] = 0.f;

  const int tkA = SPARSE ? s_tok[ar] : (row0 + ar);

  for (int k0 = 0; k0 < DIN; k0 += 16) {
    float4 va = *(const float4*)&x[(size_t)tkA * DIN + k0 + ak];
    float4 vb = *(const float4*)&Wm[(size_t)(k0 + bk) * DOUT + col0 + bc4];
    sA[ar][ak]     = va.x; sA[ar][ak + 1] = va.y;
    sA[ar][ak + 2] = va.z; sA[ar][ak + 3] = va.w;
    sB[bk][bc4]     = vb.x; sB[bk][bc4 + 1] = vb.y;
    sB[bk][bc4 + 2] = vb.z; sB[bk][bc4 + 3] = vb.w;
    __syncthreads();
#pragma unroll
    for (int kk = 0; kk < 16; kk++) {
      float a0 = sA[tm * 4 + 0][kk], a1 = sA[tm * 4 + 1][kk];
      float a2 = sA[tm * 4 + 2][kk], a3 = sA[tm * 4 + 3][kk];
#pragma unroll
      for (int n = 0; n < 4; n++) {
        float b = sB[kk][tn * 4 + n];
        acc[0][n] += a0 * b; acc[1][n] += a1 * b;
        acc[2][n] += a2 * b; acc[3][n] += a3 * b;
      }
    }
    __syncthreads();
  }

#pragma unroll
  for (int m = 0; m < 4; m++) {
    int lrow = tm * 4 + m;
#pragma unroll
    for (int n = 0; n < 4; n++) {
      int col = col0 + tn * 4 + n;
      float bcv = SPARSE ? bias[e * DOUT + col] : bias[col];
      if (SPARSE) {
        if (row0 + lrow < cnt) {
          atomicAdd(&y[(size_t)s_tok[lrow] * DOUT + col],
                    s_w[lrow] * (acc[m][n] + bcv));
        }
      } else {
        y[(size_t)(row0 + lrow) * DOUT + col] = acc[m][n] + bcv;
      }
    }
  }
}

// Tier-C: zero d_out (safe, loud validation failure — never faults).
__global__ void k_zero(float* __restrict__ y, int n) {
  for (int i = blockIdx.x * blockDim.x + threadIdx.x; i < n;
       i += gridDim.x * blockDim.x)
    y[i] = 0.f;
}

extern "C" void kernel_launch(void* const* d_in, const int* in_sizes, int n_in,
                              void* d_out, int out_size, void* d_ws, size_t ws_size,
                              hipStream_t stream) {
  (void)in_sizes; (void)n_in;
  const float* x   = (const float*)d_in[0];
  const float* Wsh = (const float*)d_in[1];
  const float* bsh = (const float*)d_in[2];
  const float* Wr  = (const float*)d_in[3];
  const float* br  = (const float*)d_in[4];
  const float* Wsp = (const float*)d_in[5];
  const float* bsp = (const float*)d_in[6];
  float* y = (float*)d_out;

  char* ws = (char*)d_ws;
  size_t off = 0;
  auto alloc = [&](size_t bytes) {
    off = (off + 255) & ~(size_t)255;
    void* p = ws + off;
    off += bytes;
    return p;
  };
  int*      counts   = (int*)alloc(NSP * sizeof(int));
  int*      tok_list = (int*)alloc((size_t)NSP * NT * sizeof(int));
  float*    w_list   = (float*)alloc((size_t)NSP * NT * sizeof(float));
  const size_t NEED_FB = off;                     // ~0.53 MB
  _Float16* xh       = (_Float16*)alloc((size_t)NT * DIN * 2);
  _Float16* wth      = (_Float16*)alloc((size_t)9 * DOUT * DIN * 2);
  const size_t NEED_FAST = off;                   // ~110 MB

  if (ws_size < NEED_FB) {                        // Tier C: no usable scratch
    k_zero<<<2048, 256, 0, stream>>>(y, out_size);
    return;
  }

  hipMemsetAsync(counts, 0, NSP * sizeof(int), stream);
  k_router<<<NT / 4, 256, 0, stream>>>(x, Wr, br, counts, tok_list, w_list);

  if (ws_size >= NEED_FAST) {                     // Tier A: fp16 MFMA path
    k_convert_x<<<(NT * DIN / 8) / 256, 256, 0, stream>>>(x, xh);
    k_convert_w<<<dim3(DIN / 32, DOUT / 32, 1), 256, 0, stream>>>(Wsh, wth, 0);
    k_convert_w<<<dim3(DIN / 32, DOUT / 32, NSP), 256, 0, stream>>>(Wsp, wth, 1);
    // shared expert: plain store (initializes all of y)
    k_moe_gemm<false><<<dim3(DOUT / 128, NT / 128, 1), 256, 0, stream>>>(
        xh, wth, bsh, counts, tok_list, w_list, y);
    // sparse experts: gathered rows, atomicAdd epilogue (ordered after shared)
    k_moe_gemm<true><<<dim3(DOUT / 128, NT / 128, NSP), 256, 0, stream>>>(
        xh, wth, bsp, counts, tok_list, w_list, y);
  } else {                                        // Tier B: fp32 fallback GEMM
    k_fb_gemm<false><<<dim3(DOUT / 64, NT / 64, 1), 256, 0, stream>>>(
        x, Wsh, bsh, counts, tok_list, w_list, y);
    k_fb_gemm<true><<<dim3(DOUT / 64, NT / 64, NSP), 256, 0, stream>>>(
        x, Wsp, bsp, counts, tok_list, w_list, y);
  }
}

// Round 9
// 785.266 us; speedup vs baseline: 1.5530x; 1.0069x over previous
//
#include <hip/hip_runtime.h>
#include <hip/hip_bf16.h>
#include <stdint.h>

#define NT   8192
#define DIN  2048
#define DOUT 2048
#define NSP  8
#define BK   64

// fp16 MFMA fragments: 8 halves = 4 VGPRs (guide §3, same mapping as bf16).
typedef _Float16 f16x8 __attribute__((ext_vector_type(8)));
typedef float    f32x4 __attribute__((ext_vector_type(4)));

static_assert(sizeof(f16x8) == 16, "f16x8 must be 16B");

__device__ __forceinline__ f32x4 mfma_f16(f16x8 a, f16x8 b, f32x4 c) {
  return __builtin_amdgcn_mfma_f32_16x16x32_f16(a, b, c, 0, 0, 0);
}

// async global->LDS, 16B per lane. HW semantics (m104/m108): dest is
// wave-uniform base + lane*16 — our per-lane loff is exactly lane-linear.
__device__ __forceinline__ void async16(const void* g, void* l) {
  __builtin_amdgcn_global_load_lds(
      (const __attribute__((address_space(1))) uint32_t*)g,
      (__attribute__((address_space(3))) uint32_t*)l, 16, 0, 0);
}

// ---------------- x convert: fp32 [T][D] -> fp16 [T][D] ----------------------
__global__ void k_convert_x(const float* __restrict__ x,
                            _Float16* __restrict__ xh) {
  int idx = blockIdx.x * blockDim.x + threadIdx.x;  // 8 elems / thread
  const float4* xv = (const float4*)x;
  float4 v0 = xv[2 * idx], v1 = xv[2 * idx + 1];
  union { _Float16 h[8]; int4 q; } H;
  H.h[0] = (_Float16)v0.x; H.h[1] = (_Float16)v0.y;
  H.h[2] = (_Float16)v0.z; H.h[3] = (_Float16)v0.w;
  H.h[4] = (_Float16)v1.x; H.h[5] = (_Float16)v1.y;
  H.h[6] = (_Float16)v1.z; H.h[7] = (_Float16)v1.w;
  ((int4*)xh)[idx] = H.q;
}

// -------- W convert + transpose: W [e][k][o] fp32 -> Wt[(eoff+e)][o][k] fp16 -
__global__ void k_convert_w(const float* __restrict__ W,
                            _Float16* __restrict__ wth, int eoff) {
  __shared__ float tile[32][33];   // 33-stride: transpose read hits 32 banks
  const int e = blockIdx.z;
  const float* Wm = W + (size_t)e * DIN * DOUT;
  const int k0 = blockIdx.x * 32, o0 = blockIdx.y * 32;
  const int r = threadIdx.x >> 5, c = threadIdx.x & 31;
#pragma unroll
  for (int i = 0; i < 4; i++) {
    int rr = r + i * 8;
    tile[rr][c] = Wm[(size_t)(k0 + rr) * DOUT + o0 + c];
  }
  __syncthreads();
  const size_t obase = (size_t)(eoff + e) * DOUT;
#pragma unroll
  for (int i = 0; i < 4; i++) {
    int rr = r + i * 8;                      // row within o-tile
    float val = tile[c][rr];                 // = W[k0+c][o0+rr]
    wth[(obase + o0 + rr) * (size_t)DIN + (size_t)(k0 + c)] = (_Float16)val;
  }
}

// ---------------- router: gates + per-expert token lists ---------------------
__global__ void k_router(const float* __restrict__ x, const float* __restrict__ Wr,
                         const float* __restrict__ br,
                         int* __restrict__ counts, int* __restrict__ tok_list,
                         float* __restrict__ w_list) {
  const int wave = threadIdx.x >> 6, lane = threadIdx.x & 63;
  const int t = blockIdx.x * 4 + wave;
  const float* xrow = x + (size_t)t * DIN;
  float acc[NSP];
#pragma unroll
  for (int e = 0; e < NSP; e++) acc[e] = 0.f;
  for (int d = lane; d < DIN; d += 64) {
    float xv = xrow[d];
    const float* wr = Wr + d * NSP;
#pragma unroll
    for (int e = 0; e < NSP; e++) acc[e] += xv * wr[e];
  }
#pragma unroll
  for (int e = 0; e < NSP; e++) {
#pragma unroll
    for (int off = 32; off > 0; off >>= 1) acc[e] += __shfl_xor(acc[e], off, 64);
  }
  if (lane == 0) {
    float lg[NSP], mx = -1e30f;
#pragma unroll
    for (int e = 0; e < NSP; e++) { lg[e] = acc[e] + br[e]; mx = fmaxf(mx, lg[e]); }
    float p[NSP], s = 0.f;
#pragma unroll
    for (int e = 0; e < NSP; e++) { p[e] = expf(lg[e] - mx); s += p[e]; }
    int i0 = 0;
#pragma unroll
    for (int e = 1; e < NSP; e++) if (p[e] > p[i0]) i0 = e;   // strict >: first max
    int i1 = (i0 == 0) ? 1 : 0;                               // == lax.top_k ties
#pragma unroll
    for (int e = 0; e < NSP; e++) if (e != i0 && p[e] > p[i1]) i1 = e;
    float p0 = p[i0] / s, p1 = p[i1] / s;
    float denom = p0 + p1 + 1e-6f;
    float w0 = p0 / denom, w1 = p1 / denom;
    int s0 = atomicAdd(&counts[i0], 1);
    tok_list[i0 * NT + s0] = t; w_list[i0 * NT + s0] = w0;
    int s1 = atomicAdd(&counts[i1], 1);
    tok_list[i1 * NT + s1] = t; w_list[i1 * NT + s1] = w1;
  }
}

// ------------- fp16 MFMA GEMM (m97 shape: 128x128 tile, BK=64, 4 waves) ------
// A = x rows (gathered for sparse), B^T = Wt[wi] ([o][k], k contiguous).
// R8 counters: 2-phase stage+barrier-bound (MfmaUtil 26%, VALU 14%, bank-conf
// 0). Occupancy was pinned at 3 blk/CU by launch_bounds — raise to 4 blk/CU
// (LDS 33.8KB x 4 = 135KB < 160KB, VGPR 60 << 128-cap) for cross-block
// latency overlap (m114 mechanism).
template <bool SPARSE>
__global__ __launch_bounds__(256, 4) void k_moe_gemm(
    const _Float16* __restrict__ xh, const _Float16* __restrict__ wth,
    const float* __restrict__ bias, const int* __restrict__ counts,
    const int* __restrict__ tok_list, const float* __restrict__ w_list,
    float* __restrict__ y) {
  const int e = SPARSE ? blockIdx.z : 0;
  const int wi = SPARSE ? (1 + e) : 0;
  int cnt = NT;
  if (SPARSE) {
    cnt = counts[e];
    if ((int)blockIdx.y * 128 >= cnt) return;
  }
  const int row0 = blockIdx.y * 128;
  const int col0 = blockIdx.x * 128;

  __shared__ __align__(16) _Float16 sA[128 * BK];
  __shared__ __align__(16) _Float16 sB[128 * BK];
  __shared__ int   s_tok[128];
  __shared__ float s_w[128];

  const int tid = threadIdx.x;
  const int wave = tid >> 6, lane = tid & 63;

  if (SPARSE) {
    if (tid < 128) {
      int slot = row0 + tid;
      int tk = 0; float w = 0.f;
      if (slot < cnt) { tk = tok_list[e * NT + slot]; w = w_list[e * NT + slot]; }
      s_tok[tid] = tk; s_w[tid] = w;
    }
    __syncthreads();
  }

  // Staging: wave owns rows [wave*32,+32), 4 issues x 8 rows per array.
  // Row = 128B = 8 chunks of 16B; physical slot p holds logical chunk p^(r&7).
  // Source pre-swizzled so LDS dest stays lane-linear (m173 / rule #21):
  // dest byte = base_j + lane*16 exactly (row stride 128B = 8 lanes x 16B).
  const int lr = lane >> 3, pp = lane & 7;
  const _Float16* gA[4]; const _Float16* gB[4];
  int loff[4];
#pragma unroll
  for (int j = 0; j < 4; j++) {
    int r = wave * 32 + j * 8 + lr;
    int xoff = ((pp ^ (r & 7)) << 3);  // element offset of swizzled 8-elem chunk
    int tk = SPARSE ? s_tok[r] : (row0 + r);
    gA[j] = xh + (size_t)tk * DIN + xoff;
    gB[j] = wth + ((size_t)wi * DOUT + (size_t)(col0 + r)) * DIN + xoff;
    loff[j] = r * BK + pp * 8;  // fp16 index; byte = r*128 + pp*16
  }

  f32x4 acc[4][4];
#pragma unroll
  for (int m = 0; m < 4; m++)
#pragma unroll
    for (int n = 0; n < 4; n++) acc[m][n] = (f32x4){0.f, 0.f, 0.f, 0.f};

  const int wm = (wave >> 1) * 64, wn = (wave & 1) * 64;
  const int fr = lane & 15, fg = lane >> 4;   // frag row / 8-elem k-group

  for (int kt = 0; kt < DIN / BK; kt++) {
    const int k0 = kt * BK;
#pragma unroll
    for (int j = 0; j < 4; j++) {
      async16(gA[j] + k0, &sA[loff[j]]);
      async16(gB[j] + k0, &sB[loff[j]]);
    }
    __syncthreads();  // compiler drains vmcnt before barrier

#pragma unroll
    for (int ks = 0; ks < 2; ks++) {
      f16x8 ah[4], bh[4];
#pragma unroll
      for (int m = 0; m < 4; m++) {
        int r = wm + m * 16 + fr;
        int sl = (((ks * 4 + fg) ^ (r & 7)) << 3);
        ah[m] = *(const f16x8*)&sA[r * BK + sl];
      }
#pragma unroll
      for (int n = 0; n < 4; n++) {
        int c = wn + n * 16 + fr;
        int sl = (((ks * 4 + fg) ^ (c & 7)) << 3);
        bh[n] = *(const f16x8*)&sB[c * BK + sl];
      }
#pragma unroll
      for (int m = 0; m < 4; m++)
#pragma unroll
        for (int n = 0; n < 4; n++)
          acc[m][n] = mfma_f16(ah[m], bh[n], acc[m][n]);
    }
    __syncthreads();
  }

  // Epilogue. C/D layout: col = lane&15, row = (lane>>4)*4 + reg (m89-verified).
#pragma unroll
  for (int n = 0; n < 4; n++) {
    int col = col0 + wn + n * 16 + fr;
    float bc = SPARSE ? bias[e * DOUT + col] : bias[col];
#pragma unroll
    for (int m = 0; m < 4; m++) {
#pragma unroll
      for (int q = 0; q < 4; q++) {
        int lrow = wm + m * 16 + fg * 4 + q;
        float v = acc[m][n][q];
        if (SPARSE) {
          if (row0 + lrow < cnt) {
            float g = s_w[lrow];
            atomicAdd(&y[(size_t)s_tok[lrow] * DOUT + col], g * (v + bc));
          }
        } else {
          y[(size_t)(row0 + lrow) * DOUT + col] = v + bc;  // N_SHARED==1
        }
      }
    }
  }
}

// ============ Tier-B fallback: fp32 vector GEMM, tiny workspace ==============
template <bool SPARSE>
__global__ void k_fb_gemm(const float* __restrict__ x, const float* __restrict__ W,
                          const float* __restrict__ bias,
                          const int* __restrict__ counts,
                          const int* __restrict__ tok_list,
                          const float* __restrict__ w_list,
                          float* __restrict__ y) {
  const int e = SPARSE ? blockIdx.z : 0;
  int cnt = NT;
  if (SPARSE) {
    cnt = counts[e];
    if ((int)blockIdx.y * 64 >= cnt) return;
  }
  const int row0 = blockIdx.y * 64, col0 = blockIdx.x * 64;
  const float* Wm = W + (SPARSE ? (size_t)e * DIN * DOUT : 0);

  __shared__ float sA[64][17];
  __shared__ float sB[16][65];
  __shared__ int   s_tok[64];
  __shared__ float s_w[64];

  const int tid = threadIdx.x;
  if (SPARSE) {
    if (tid < 64) {
      int slot = row0 + tid;
      int tk = 0; float w = 0.f;
      if (slot < cnt) { tk = tok_list[e * NT + slot]; w = w_list[e * NT + slot]; }
      s_tok[tid] = tk; s_w[tid] = w;
    }
    __syncthreads();
  }

  const int ar = tid >> 2, ak = (tid & 3) * 4;
  const int bk = tid >> 4, bc4 = (tid & 15) * 4;
  const int tm = tid >> 4, tn = tid & 15;

  float acc[4][4];
#pragma unroll
  for (int m = 0; m < 4; m++)
#pragma unroll
    for (int n = 0; n < 4; n++) acc[m][n] = 0.f;

  const int tkA = SPARSE ? s_tok[ar] : (row0 + ar);

  for (int k0 = 0; k0 < DIN; k0 += 16) {
    float4 va = *(const float4*)&x[(size_t)tkA * DIN + k0 + ak];
    float4 vb = *(const float4*)&Wm[(size_t)(k0 + bk) * DOUT + col0 + bc4];
    sA[ar][ak]     = va.x; sA[ar][ak + 1] = va.y;
    sA[ar][ak + 2] = va.z; sA[ar][ak + 3] = va.w;
    sB[bk][bc4]     = vb.x; sB[bk][bc4 + 1] = vb.y;
    sB[bk][bc4 + 2] = vb.z; sB[bk][bc4 + 3] = vb.w;
    __syncthreads();
#pragma unroll
    for (int kk = 0; kk < 16; kk++) {
      float a0 = sA[tm * 4 + 0][kk], a1 = sA[tm * 4 + 1][kk];
      float a2 = sA[tm * 4 + 2][kk], a3 = sA[tm * 4 + 3][kk];
#pragma unroll
      for (int n = 0; n < 4; n++) {
        float b = sB[kk][tn * 4 + n];
        acc[0][n] += a0 * b; acc[1][n] += a1 * b;
        acc[2][n] += a2 * b; acc[3][n] += a3 * b;
      }
    }
    __syncthreads();
  }

#pragma unroll
  for (int m = 0; m < 4; m++) {
    int lrow = tm * 4 + m;
#pragma unroll
    for (int n = 0; n < 4; n++) {
      int col = col0 + tn * 4 + n;
      float bcv = SPARSE ? bias[e * DOUT + col] : bias[col];
      if (SPARSE) {
        if (row0 + lrow < cnt) {
          atomicAdd(&y[(size_t)s_tok[lrow] * DOUT + col],
                    s_w[lrow] * (acc[m][n] + bcv));
        }
      } else {
        y[(size_t)(row0 + lrow) * DOUT + col] = acc[m][n] + bcv;
      }
    }
  }
}

// Tier-C: zero d_out (safe, loud validation failure — never faults).
__global__ void k_zero(float* __restrict__ y, int n) {
  for (int i = blockIdx.x * blockDim.x + threadIdx.x; i < n;
       i += gridDim.x * blockDim.x)
    y[i] = 0.f;
}

extern "C" void kernel_launch(void* const* d_in, const int* in_sizes, int n_in,
                              void* d_out, int out_size, void* d_ws, size_t ws_size,
                              hipStream_t stream) {
  (void)in_sizes; (void)n_in;
  const float* x   = (const float*)d_in[0];
  const float* Wsh = (const float*)d_in[1];
  const float* bsh = (const float*)d_in[2];
  const float* Wr  = (const float*)d_in[3];
  const float* br  = (const float*)d_in[4];
  const float* Wsp = (const float*)d_in[5];
  const float* bsp = (const float*)d_in[6];
  float* y = (float*)d_out;

  char* ws = (char*)d_ws;
  size_t off = 0;
  auto alloc = [&](size_t bytes) {
    off = (off + 255) & ~(size_t)255;
    void* p = ws + off;
    off += bytes;
    return p;
  };
  int*      counts   = (int*)alloc(NSP * sizeof(int));
  int*      tok_list = (int*)alloc((size_t)NSP * NT * sizeof(int));
  float*    w_list   = (float*)alloc((size_t)NSP * NT * sizeof(float));
  const size_t NEED_FB = off;                     // ~0.53 MB
  _Float16* xh       = (_Float16*)alloc((size_t)NT * DIN * 2);
  _Float16* wth      = (_Float16*)alloc((size_t)9 * DOUT * DIN * 2);
  const size_t NEED_FAST = off;                   // ~110 MB

  if (ws_size < NEED_FB) {                        // Tier C: no usable scratch
    k_zero<<<2048, 256, 0, stream>>>(y, out_size);
    return;
  }

  hipMemsetAsync(counts, 0, NSP * sizeof(int), stream);
  k_router<<<NT / 4, 256, 0, stream>>>(x, Wr, br, counts, tok_list, w_list);

  if (ws_size >= NEED_FAST) {                     // Tier A: fp16 MFMA path
    k_convert_x<<<(NT * DIN / 8) / 256, 256, 0, stream>>>(x, xh);
    k_convert_w<<<dim3(DIN / 32, DOUT / 32, 1), 256, 0, stream>>>(Wsh, wth, 0);
    k_convert_w<<<dim3(DIN / 32, DOUT / 32, NSP), 256, 0, stream>>>(Wsp, wth, 1);
    // shared expert: plain store (initializes all of y)
    k_moe_gemm<false><<<dim3(DOUT / 128, NT / 128, 1), 256, 0, stream>>>(
        xh, wth, bsh, counts, tok_list, w_list, y);
    // sparse experts: gathered rows, atomicAdd epilogue (ordered after shared)
    k_moe_gemm<true><<<dim3(DOUT / 128, NT / 128, NSP), 256, 0, stream>>>(
        xh, wth, bsp, counts, tok_list, w_list, y);
  } else {                                        // Tier B: fp32 fallback GEMM
    k_fb_gemm<false><<<dim3(DOUT / 64, NT / 64, 1), 256, 0, stream>>>(
        x, Wsh, bsh, counts, tok_list, w_list, y);
    k_fb_gemm<true><<<dim3(DOUT / 64, NT / 64, NSP), 256, 0, stream>>>(
        x, Wsp, bsp, counts, tok_list, w_list, y);
  }
}